// Round 12
// baseline (247.671 us; speedup 1.0000x reference)
//
#include <hip/hip_runtime.h>

#define NW 14
#define NL 3
#define NGAT 42            // 3 layers x 14 rotation gates
#define DIM 16384          // 2^14 amplitudes
#define BLOCK 1024

// ---------------------------------------------------------------------------
// MFMA formulation with writer-frame layouts + per-batch BANK-CONFLICT
// ENGINEERING (round 12).
//
// Per batch, duality correction makes every coset see the same 16x16 matrix
// W = U3(x)U2(x)U1(x)U0 -> batch = complex GEMM D[16x1024] = W x S as bf16
// hi/lo splits on matrix cores (3 mfma per r/i output), fp32 state in LDS.
//
// Layout after batch w: Lambda_w = T_w o F_w^{-1},
//   T_w(y,e) = (y<<4) ^ e ^ sigma_w(n),  n = y low 4 bits,
//   sigma_w: linear 4->4, range restricted to e-bits {1,2,3} (bit 0 would
//   swap complex pairs inside the writer's b128 stores).
// Writer stores & batch-0 in-place reads are bank-balanced for ANY such
// sigma (cosets of {q<<2} ^ sigma(n) partition the 16 bank-groups evenly).
// Reader r's 16 scattered b64 reads: conflict profile determined ONLY by
// the slot-low4 (bank-group) projections of 6 lane-varying XOR vectors
//   {Lambda_w(cvec_r[0..3]) (n-bits), Lambda_w(basis_r[2,3]) (q-bits)};
// conflict-FREE iff they span GF(2)^4 (4 lanes per 2-bank group = 4-clk
// minimum). make_planp searches sigma_w per boundary for rank 4 (default
// first -> no regression; then 256 scrambled candidates; keep best rank).
// Round 11 measured 1.97e7 conflicts (~30us) from exactly these reads.
// ---------------------------------------------------------------------------

typedef float        f4  __attribute__((ext_vector_type(4)));
typedef short        s8v __attribute__((ext_vector_type(8)));
typedef unsigned int u4v __attribute__((ext_vector_type(4)));

constexpr int parity14(int v) { int p = 0; for (int i = 0; i < NW; ++i) p ^= (v >> i) & 1; return p; }
constexpr int hibit(int v) { int h = -1; for (int i = 0; i < NW; ++i) if ((v >> i) & 1) h = i; return h; }

struct Lin { int col[NW]; };

constexpr int lin_apply(const Lin& M, int x) {
    int r = 0;
    for (int i = 0; i < NW; ++i) if ((x >> i) & 1) r ^= M.col[i];
    return r;
}
constexpr Lin lin_inverse(const Lin& M) {
    int E[NW] = {}, P[NW] = {};
    for (int i = 0; i < NW; ++i) {
        int v = M.col[i], p = 1 << i;
        while (v) {
            int h = hibit(v);
            if (!E[h]) { E[h] = v; P[h] = p; break; }
            v ^= E[h]; p ^= P[h];
        }
    }
    Lin R{};
    for (int i = 0; i < NW; ++i) {
        int v = 1 << i, p = 0;
        while (v) { int h = hibit(v); v ^= E[h]; p ^= P[h]; }
        R.col[i] = p;
    }
    return R;
}
constexpr Lin lin_compose(const Lin& A, const Lin& B) {
    Lin R{};
    for (int i = 0; i < NW; ++i) R.col[i] = lin_apply(A, B.col[i]);
    return R;
}

struct BatchP {
    int ngates;
    int gidx[4];
    unsigned rdy[10];   // byte: 8 * Lambda_{r-1}(cvec_r[k])  (y-bit directions)
    unsigned rde[16];   // byte: 8 * Lambda_{r-1}(combo_r[e]) (e-directions)
    unsigned long long spack;  // sigma_w packed: 4 bits per n (16 entries)
};
struct PlanP {
    BatchP b[12];
    unsigned stB[14];   // staging: byte 8 * Lambda_0(1<<bit)
    unsigned ykey[14];  // tail: parity mask over key = y | (q<<10)
    int zsel[14];       // tail: Walsh index from basis[0,1] parities
};

constexpr PlanP make_planp() {
    PlanP P{};
    int R[NW] = {}, C[NW] = {};
    for (int p = 0; p < NW; ++p) { R[p] = 1 << p; C[p] = 1 << p; }

    int basisA[12][4] = {}; int comboA[12][16] = {}; int cvecA[12][10] = {};
    Lin F[12] = {};
    int bi = 0;
    for (int l = 0; l < NL; ++l) {
        const int sizes[4] = {4, 4, 4, 2};
        int w0 = 0;
        for (int s = 0; s < 4; ++s) {
            const int ng = sizes[s];
            P.b[bi].ngates = ng;
            int basis[4] = {}, rr[4] = {};
            for (int j = 0; j < ng; ++j) {
                int w = w0 + j, p = 13 - w;
                basis[j] = C[p];
                rr[j] = R[p];
                P.b[bi].gidx[j] = l * NW + w;
            }
            // echelon for independence
            int ech[4] = {}; int ne = 0;
            for (int j = 0; j < ng; ++j) {
                int v = basis[j];
                bool ch = true;
                while (ch) { ch = false;
                    for (int k = 0; k < ne; ++k)
                        if (v && ((v >> hibit(ech[k])) & 1)) { v ^= ech[k]; ch = true; }
                }
                ech[ne++] = v;
            }
            // pad to 4 from null space of gate parity masks
            int nb = ng;
            for (int cand = 1; cand < DIM && nb < 4; ++cand) {
                bool ok = true;
                for (int j = 0; j < ng; ++j) if (parity14(cand & rr[j])) { ok = false; break; }
                if (!ok) continue;
                int v = cand;
                bool ch = true;
                while (ch) { ch = false;
                    for (int k = 0; k < ne; ++k)
                        if (v && ((v >> hibit(ech[k])) & 1)) { v ^= ech[k]; ch = true; }
                }
                if (v) { basis[nb++] = cand; ech[ne++] = v; }
            }
            // pivots & non-pivot positions
            int piv[4] = {};
            for (int k = 0; k < 4; ++k) piv[k] = hibit(ech[k]);
            for (int a = 0; a < 4; ++a)
                for (int b2 = a + 1; b2 < 4; ++b2)
                    if (piv[b2] < piv[a]) { int t = piv[a]; piv[a] = piv[b2]; piv[b2] = t; }
            int npp[10] = {}; int nn = 0;
            for (int bit = 0; bit < NW; ++bit) {
                bool isp = false;
                for (int k = 0; k < 4; ++k) if (piv[k] == bit) isp = true;
                if (!isp) npp[nn++] = bit;
            }
            // duality-corrected coset directions
            for (int k = 0; k < 10; ++k) {
                int c = 1 << npp[k];
                for (int j = 0; j < ng; ++j) if ((rr[j] >> npp[k]) & 1) c ^= basis[j];
                cvecA[bi][k] = c;
            }
            for (int e = 0; e < 16; ++e) {
                int v = 0;
                for (int j = 0; j < 4; ++j) if ((e >> j) & 1) v ^= basis[j];
                comboA[bi][e] = v;
            }
            for (int j = 0; j < 4; ++j) basisA[bi][j] = basis[j];
            for (int j = 0; j < 4; ++j) F[bi].col[j] = basis[j];
            for (int k = 0; k < 10; ++k) F[bi].col[4 + k] = cvecA[bi][k];
            w0 += ng;
            ++bi;
        }
        // CNOT chain (w,w+1) w=0..12 then (13,0)
        for (int w = 0; w < NW; ++w) {
            int c = w, t = (w + 1) % NW;
            int pc = 13 - c, pt = 13 - t;
            R[pt] ^= R[pc];
            C[pc] ^= C[pt];
        }
    }

    // ---- sigma search per writer w (reader r = w+1) ----
    unsigned sigcol[12][4] = {};
    for (int w = 0; w < 12; ++w) { sigcol[w][0] = 2; sigcol[w][1] = 4; sigcol[w][2] = 8; sigcol[w][3] = 0; }
    for (int w = 0; w < 11; ++w) {
        const int r = w + 1;
        Lin Fi = lin_inverse(F[w]);
        int uvec[6] = { cvecA[r][0], cvecA[r][1], cvecA[r][2], cvecA[r][3],
                        basisA[r][2], basisA[r][3] };
        int ep[6] = {}, np[6] = {};
        for (int i = 0; i < 6; ++i) {
            int v = lin_apply(Fi, uvec[i]);
            ep[i] = v & 15;
            np[i] = (v >> 4) & 15;
        }
        int bestrank = -1; unsigned best[4] = {2, 4, 8, 0};
        for (int c = 0; c < 256; ++c) {
            const unsigned code = (c == 0) ? 0x111u : ((unsigned)((unsigned)c * 2654435761u) & 4095u);
            unsigned col[4] = { (code & 7u) << 1, ((code >> 3) & 7u) << 1,
                                ((code >> 6) & 7u) << 1, ((code >> 9) & 7u) << 1 };
            int e2[4] = {}; int rank = 0;
            for (int i = 0; i < 6; ++i) {
                int s = 0;
                for (int k = 0; k < 4; ++k) if ((np[i] >> k) & 1) s ^= (int)col[k];
                int v = ep[i] ^ s;
                while (v) {
                    int h = hibit(v);
                    if (!e2[h]) { e2[h] = v; ++rank; break; }
                    v ^= e2[h];
                }
            }
            if (rank > bestrank) {
                bestrank = rank;
                for (int k = 0; k < 4; ++k) best[k] = col[k];
            }
            if (bestrank == 4) break;
        }
        for (int k = 0; k < 4; ++k) sigcol[w][k] = best[k];
    }

    // per-batch T_w and packed runtime sigma tables
    Lin Tw[12] = {};
    for (int w = 0; w < 12; ++w) {
        for (int j = 0; j < 4; ++j) Tw[w].col[j] = 1 << j;
        for (int k = 0; k < 10; ++k)
            Tw[w].col[4 + k] = (1 << (4 + k)) ^ (k < 4 ? (int)sigcol[w][k] : 0);
        unsigned long long sp = 0;
        for (int nv = 0; nv < 16; ++nv) {
            unsigned s = 0;
            for (int k = 0; k < 4; ++k) if ((nv >> k) & 1) s ^= sigcol[w][k];
            sp |= (unsigned long long)s << (nv * 4);
        }
        P.b[w].spack = sp;
    }

    // Lambda_w = T_w o F_w^{-1}; staging uses Lambda_0, reader r uses Lambda_{r-1}
    {
        Lin L0 = lin_compose(Tw[0], lin_inverse(F[0]));
        for (int bit = 0; bit < NW; ++bit) P.stB[bit] = (unsigned)lin_apply(L0, 1 << bit) * 8u;
    }
    for (int r = 1; r < 12; ++r) {
        Lin Lw = lin_compose(Tw[r - 1], lin_inverse(F[r - 1]));
        for (int k = 0; k < 10; ++k) P.b[r].rdy[k] = (unsigned)lin_apply(Lw, cvecA[r][k]) * 8u;
        for (int e = 0; e < 16; ++e) P.b[r].rde[e] = (unsigned)lin_apply(Lw, comboA[r][e]) * 8u;
    }
    for (int w = 0; w < NW; ++w) {
        int zrw = R[13 - w];
        unsigned ym = 0;
        for (int k = 0; k < 10; ++k) ym |= (unsigned)parity14(cvecA[11][k] & zrw) << k;
        int qm = parity14(basisA[11][2] & zrw) | (parity14(basisA[11][3] & zrw) << 1);
        P.ykey[w] = ym | ((unsigned)qm << 10);
        P.zsel[w] = parity14(basisA[11][0] & zrw) | (parity14(basisA[11][1] & zrw) << 1);
    }
    return P;
}

constexpr PlanP PL = make_planp();

// fp32 (r,i) -> packed bf16 hi dword [bf16(i)|bf16(r)] + lo dword (residual).
__device__ __forceinline__ void splitpk(float r, float i, unsigned& hi, unsigned& lo) {
#if __has_builtin(__builtin_amdgcn_cvt_pk_bf16_f32)
    hi = __builtin_bit_cast(unsigned, __builtin_amdgcn_cvt_pk_bf16_f32(r, i));
    const float lr = r - __uint_as_float(hi << 16);
    const float li = i - __uint_as_float(hi & 0xffff0000u);
    lo = __builtin_bit_cast(unsigned, __builtin_amdgcn_cvt_pk_bf16_f32(lr, li));
#else
    const unsigned tr = __float_as_uint(r);
    const unsigned ti = __float_as_uint(i);
    hi = __builtin_amdgcn_perm(ti, tr, 0x07060302u);
    const float lr = r - __uint_as_float(tr & 0xffff0000u);
    const float li = i - __uint_as_float(ti & 0xffff0000u);
    const unsigned ur = __float_as_uint(lr) + 0x8000u;
    const unsigned ui = __float_as_uint(li) + 0x8000u;
    lo = __builtin_amdgcn_perm(ui, ur, 0x07060302u);
#endif
}

__device__ __forceinline__ f4 mf(u4v a, u4v b, f4 c) {
    return __builtin_amdgcn_mfma_f32_16x16x32_bf16(
        __builtin_bit_cast(s8v, a), __builtin_bit_cast(s8v, b), c, 0, 0, 0);
}

// scattered-read base for reader batch B: XOR-select over y-bits (n,wid) and
// q-part; per-tile t adds rdy[4]/rdy[5]; 4 entries at {0, rde1, rde2, rde3}.
#define RD_SREP(B)                                                     \
    unsigned srep = 0;                                                 \
    srep ^= (n & 1u)   ? B.rdy[0] : 0u;                                \
    srep ^= (n & 2u)   ? B.rdy[1] : 0u;                                \
    srep ^= (n & 4u)   ? B.rdy[2] : 0u;                                \
    srep ^= (n & 8u)   ? B.rdy[3] : 0u;                                \
    srep ^= (wid & 1u) ? B.rdy[6] : 0u;                                \
    srep ^= (wid & 2u) ? B.rdy[7] : 0u;                                \
    srep ^= (wid & 4u) ? B.rdy[8] : 0u;                                \
    srep ^= (wid & 8u) ? B.rdy[9] : 0u;                                \
    srep ^= (q & 1u)   ? B.rde[4] : 0u;                                \
    srep ^= (q & 2u)   ? B.rde[8] : 0u;

template <int BI>
__device__ __forceinline__ void mfma_batch(char* __restrict__ lds, const float* __restrict__ gm,
                                           unsigned* __restrict__ atab) {
    constexpr BatchP B = PL.b[BI];
    const unsigned tid = threadIdx.x;
    const unsigned lane = tid & 63u, wid = tid >> 6;
    const unsigned n = lane & 15u, q = lane >> 4;

    __syncthreads();   // prev batch stores visible; prev atab reads done

    // ---- A-table build (threads 0..255), concurrent with phase A ----
    if (tid < 256) {
        const unsigned m = tid >> 4, ein = tid & 15u;
        float wr = 1.f, wi = 0.f;
        #pragma unroll
        for (int j = 0; j < 4; ++j) {
            if (j < B.ngates) {
                const unsigned mj = (m >> j) & 1u, ej = (ein >> j) & 1u;
                const float ur = gm[B.gidx[j] * 8 + (int)(mj * 4u + ej * 2u)];
                const float ui = gm[B.gidx[j] * 8 + (int)(mj * 4u + ej * 2u) + 1];
                const float nr = wr * ur - wi * ui;
                const float ni = wr * ui + wi * ur;
                wr = nr; wi = ni;
            }
        }
        if (B.ngates < 4 && (((m ^ ein) >> B.ngates) != 0u)) { wr = 0.f; wi = 0.f; }
        unsigned twr = __float_as_uint(wr) + 0x8000u;
        unsigned twi = __float_as_uint(wi) + 0x8000u;
        float lr = wr - __uint_as_float(twr & 0xffff0000u);
        float li = wi - __uint_as_float(twi & 0xffff0000u);
        unsigned tlr = __float_as_uint(lr) + 0x8000u;
        unsigned tli = __float_as_uint(li) + 0x8000u;
        const unsigned o = m * 16u + ein;
        atab[o]        = __builtin_amdgcn_perm(twi ^ 0x80000000u, twr, 0x07060302u); // (Wr_hi,-Wi_hi)
        atab[256 + o]  = __builtin_amdgcn_perm(tli ^ 0x80000000u, tlr, 0x07060302u); // (Wr_lo,-Wi_lo)
        atab[512 + o]  = __builtin_amdgcn_perm(twr, twi, 0x07060302u);               // (Wi_hi, Wr_hi)
        atab[768 + o]  = __builtin_amdgcn_perm(tlr, tli, 0x07060302u);               // (Wi_lo, Wr_lo)
    }

    // clean T_BI-frame base: batch-0 reads and ALL writer stores
    const unsigned sig = (unsigned)((B.spack >> (n * 4u)) & 15ull);
    const unsigned bnq = ((wid << 10) ^ (n << 4) ^ sig ^ (q << 2)) << 3;

    // ---- phase A: read + convert all 4 tiles (all reads precede all writes) ----
    u4v bhi[4], blo[4];
    if constexpr (BI == 0) {
        #pragma unroll
        for (int t = 0; t < 4; ++t) {
            const unsigned a0 = bnq ^ ((unsigned)t << 11);
            const f4 v01 = *(const f4*)(lds + a0);
            const f4 v23 = *(const f4*)(lds + (a0 ^ 16u));
            unsigned h0, l0, h1, l1, h2, l2, h3, l3;
            splitpk(v01.x, v01.y, h0, l0);
            splitpk(v01.z, v01.w, h1, l1);
            splitpk(v23.x, v23.y, h2, l2);
            splitpk(v23.z, v23.w, h3, l3);
            u4v h; h.x = h0; h.y = h1; h.z = h2; h.w = h3;
            u4v l; l.x = l0; l.y = l1; l.z = l2; l.w = l3;
            bhi[t] = h; blo[t] = l;
        }
    } else {
        RD_SREP(B)
        #pragma unroll
        for (int t = 0; t < 4; ++t) {
            const unsigned st = srep ^ ((t & 1) ? B.rdy[4] : 0u) ^ ((t & 2) ? B.rdy[5] : 0u);
            const float2 c0 = *(const float2*)(lds + st);
            const float2 c1 = *(const float2*)(lds + (st ^ B.rde[1]));
            const float2 c2 = *(const float2*)(lds + (st ^ B.rde[2]));
            const float2 c3 = *(const float2*)(lds + (st ^ B.rde[3]));
            unsigned h0, l0, h1, l1, h2, l2, h3, l3;
            splitpk(c0.x, c0.y, h0, l0);
            splitpk(c1.x, c1.y, h1, l1);
            splitpk(c2.x, c2.y, h2, l2);
            splitpk(c3.x, c3.y, h3, l3);
            u4v h; h.x = h0; h.y = h1; h.z = h2; h.w = h3;
            u4v l; l.x = l0; l.y = l1; l.z = l2; l.w = l3;
            bhi[t] = h; blo[t] = l;
        }
    }

    __syncthreads();   // all reads done + atab ready

    // ---- phase B: mfma + clean writer-frame b128 stores ----
    const u4v A0 = *(const u4v*)&atab[(n << 4) + (q << 2)];
    const u4v A1 = *(const u4v*)&atab[256 + (n << 4) + (q << 2)];
    const u4v A2 = *(const u4v*)&atab[512 + (n << 4) + (q << 2)];
    const u4v A3 = *(const u4v*)&atab[768 + (n << 4) + (q << 2)];

    #pragma unroll
    for (int t = 0; t < 4; ++t) {
        f4 ar = {0.f, 0.f, 0.f, 0.f};
        f4 ai = {0.f, 0.f, 0.f, 0.f};
        ar = mf(A0, bhi[t], ar);
        ai = mf(A2, bhi[t], ai);
        ar = mf(A1, bhi[t], ar);
        ai = mf(A3, bhi[t], ai);
        ar = mf(A0, blo[t], ar);
        ai = mf(A2, blo[t], ai);
        const unsigned a0 = bnq ^ ((unsigned)t << 11);
        const f4 s01 = {ar.x, ai.x, ar.y, ai.y};
        const f4 s23 = {ar.z, ai.z, ar.w, ai.w};
        *(f4*)(lds + a0)         = s01;
        *(f4*)(lds + (a0 ^ 16u)) = s23;
    }
}

// complex 2x2 butterfly
#define BFC(A, B_, ua, ub) { const float2 t0 = A, t1 = B_; \
    A.x  = ua.x * t0.x - ua.y * t0.y + ua.z * t1.x - ua.w * t1.y; \
    A.y  = ua.x * t0.y + ua.y * t0.x + ua.z * t1.y + ua.w * t1.x; \
    B_.x = ub.x * t0.x - ub.y * t0.y + ub.z * t1.x - ub.w * t1.y; \
    B_.y = ub.x * t0.y + ub.y * t0.x + ub.z * t1.y + ub.w * t1.x; }

__device__ __forceinline__ float tail_batch(char* __restrict__ lds, const float* __restrict__ gm,
                                            const float* __restrict__ g_hw) {
    constexpr BatchP B = PL.b[11];   // ngates == 2
    const unsigned tid = threadIdx.x;
    const unsigned lane = tid & 63u, wid = tid >> 6;
    const unsigned n = lane & 15u, q = lane >> 4;
    __syncthreads();
    const f4 u0a = *(const f4*)&gm[B.gidx[0] * 8];
    const f4 u0b = *(const f4*)&gm[B.gidx[0] * 8 + 4];
    const f4 u1a = *(const f4*)&gm[B.gidx[1] * 8];
    const f4 u1b = *(const f4*)&gm[B.gidx[1] * 8 + 4];
    float hwv[NW];
    #pragma unroll
    for (int w = 0; w < NW; ++w) hwv[w] = g_hw[w];
    float acc = 0.f;
    RD_SREP(B)
    #pragma unroll
    for (int t = 0; t < 4; ++t) {
        const unsigned st = srep ^ ((t & 1) ? B.rdy[4] : 0u) ^ ((t & 2) ? B.rdy[5] : 0u);
        float2 c0 = *(const float2*)(lds + st);
        float2 c1 = *(const float2*)(lds + (st ^ B.rde[1]));
        float2 c2 = *(const float2*)(lds + (st ^ B.rde[2]));
        float2 c3 = *(const float2*)(lds + (st ^ B.rde[3]));
        BFC(c0, c1, u0a, u0b)  BFC(c2, c3, u0a, u0b)   // gate 0: slot bit 0
        BFC(c0, c2, u1a, u1b)  BFC(c1, c3, u1a, u1b)   // gate 1: slot bit 1
        const float p0 = c0.x * c0.x + c0.y * c0.y;
        const float p1 = c1.x * c1.x + c1.y * c1.y;
        const float p2 = c2.x * c2.x + c2.y * c2.y;
        const float p3 = c3.x * c3.x + c3.y * c3.y;
        const float sa = p0 + p1, sb = p0 - p1, sc = p2 + p3, sd = p2 - p3;
        const float W4[4] = {sa + sc, sb + sd, sa - sc, sb - sd};
        const unsigned y = (wid << 6) | ((unsigned)t << 4) | n;
        const unsigned key = y | (q << 10);
        #pragma unroll
        for (int w = 0; w < NW; ++w) {
            const unsigned sg = ((unsigned)__popc(key & PL.ykey[w])) << 31;
            const float s = __uint_as_float(__float_as_uint(hwv[w]) ^ sg);
            acc += W4[PL.zsel[w]] * s;
        }
    }
    return acc;
}

__global__ __launch_bounds__(BLOCK) void qsim_kernel(
    const float* __restrict__ g_sr, const float* __restrict__ g_si,
    const float* __restrict__ g_params, const float* __restrict__ g_hw,
    const float* __restrict__ g_hb, float* __restrict__ g_out)
{
    extern __shared__ char lds[];                    // 16384 float2 entries (128 KiB)
    __shared__ __align__(16) float gm[NGAT * 8];
    __shared__ __align__(16) unsigned atab[1024];    // 4 A-tables, 16x32 bf16 each
    __shared__ float red[BLOCK / 64];

    const unsigned tid = threadIdx.x;
    const int b = blockIdx.x;
    const float* __restrict__ srcr = g_sr + (size_t)b * DIM;
    const float* __restrict__ srci = g_si + (size_t)b * DIM;

    // ---- gate matrices U = RZ @ RY @ RX ----
    if (tid < NGAT) {
        const float tx = g_params[tid * 3 + 0];
        const float ty = g_params[tid * 3 + 1];
        const float tz = g_params[tid * 3 + 2];
        const float cx = cosf(0.5f * tx), sx = sinf(0.5f * tx);
        const float cy = cosf(0.5f * ty), sy = sinf(0.5f * ty);
        const float cz = cosf(0.5f * tz), sz = sinf(0.5f * tz);
        const float a00r = cy * cx,  a00i = sy * sx;
        const float a01r = -sy * cx, a01i = -cy * sx;
        const float a10r = sy * cx,  a10i = -cy * sx;
        const float a11r = cy * cx,  a11i = -sy * sx;
        gm[tid * 8 + 0] = cz * a00r + sz * a00i;
        gm[tid * 8 + 1] = cz * a00i - sz * a00r;
        gm[tid * 8 + 2] = cz * a01r + sz * a01i;
        gm[tid * 8 + 3] = cz * a01i - sz * a01r;
        gm[tid * 8 + 4] = cz * a10r - sz * a10i;
        gm[tid * 8 + 5] = cz * a10i + sz * a10r;
        gm[tid * 8 + 6] = cz * a11r - sz * a11i;
        gm[tid * 8 + 7] = cz * a11i + sz * a11r;
    }

    // ---- staging: global fp32 -> Lambda_0 layout (batch 0 reads clean T_0) ----
    unsigned bb = 0;
    #pragma unroll
    for (int k = 0; k < 10; ++k) bb ^= ((tid >> k) & 1u) ? PL.stB[k + 2] : 0u;
    #pragma unroll
    for (int it = 0; it < 4; ++it) {
        const int x = (int)tid * 4 + it * 4096;
        const f4 r4 = *(const f4*)(srcr + x);
        const f4 i4 = *(const f4*)(srci + x);
        const unsigned base = bb ^ ((it & 1) ? PL.stB[12] : 0u) ^ ((it & 2) ? PL.stB[13] : 0u);
        *(float2*)(lds + base) = make_float2(r4.x, i4.x);
        *(float2*)(lds + (base ^ PL.stB[0])) = make_float2(r4.y, i4.y);
        *(float2*)(lds + (base ^ PL.stB[1])) = make_float2(r4.z, i4.z);
        *(float2*)(lds + (base ^ (PL.stB[0] ^ PL.stB[1]))) = make_float2(r4.w, i4.w);
    }

    mfma_batch<0>(lds, gm, atab);
    mfma_batch<1>(lds, gm, atab);
    mfma_batch<2>(lds, gm, atab);
    mfma_batch<3>(lds, gm, atab);
    mfma_batch<4>(lds, gm, atab);
    mfma_batch<5>(lds, gm, atab);
    mfma_batch<6>(lds, gm, atab);
    mfma_batch<7>(lds, gm, atab);
    mfma_batch<8>(lds, gm, atab);
    mfma_batch<9>(lds, gm, atab);
    mfma_batch<10>(lds, gm, atab);

    float acc = tail_batch(lds, gm, g_hw);

    // ---- reduce ----
    #pragma unroll
    for (int off = 32; off > 0; off >>= 1) acc += __shfl_down(acc, off);
    const int lane = tid & 63, wid = tid >> 6;
    if (lane == 0) red[wid] = acc;
    __syncthreads();
    if (tid == 0) {
        float s = 0.0f;
        #pragma unroll
        for (int k = 0; k < BLOCK / 64; ++k) s += red[k];
        g_out[b] = s + g_hb[0];
    }
}

extern "C" void kernel_launch(void* const* d_in, const int* in_sizes, int n_in,
                              void* d_out, int out_size, void* d_ws, size_t ws_size,
                              hipStream_t stream) {
    const float* sr = (const float*)d_in[0];
    const float* si = (const float*)d_in[1];
    const float* vp = (const float*)d_in[2];
    const float* hw = (const float*)d_in[3];
    const float* hb = (const float*)d_in[4];
    float* out = (float*)d_out;

    dim3 grid(out_size);          // 1024 batch elements, one block each
    dim3 block(BLOCK);
    size_t shmem = (size_t)DIM * sizeof(float2);  // 128 KiB dynamic LDS
    qsim_kernel<<<grid, block, shmem, stream>>>(sr, si, vp, hw, hb, out);
}